// Round 3
// baseline (525.044 us; speedup 1.0000x reference)
//
#include <hip/hip_runtime.h>
#include <hip/hip_cooperative_groups.h>
#include <math.h>

namespace cg = cooperative_groups;

#define N_NODES 650
#define DIM     512
#define E_RAW   150000
#define E_TOT   150650
#define WK      672              // padded K for dense attention matrix
#define ZG      8                // split-K for feature GEMMs: K=512, kc=64
#define ZA      6                // split-K for agg GEMMs:     K=672, kc=112
#define TILES_X 8                // DIM/64
#define TILES_Y 11               // ceil(650/64)

// ---------------- GEMM phase: P[z] = A[:, z*kc:(z+1)*kc] @ B[z*kc:(z+1)*kc, :] ----------------
// 64x64 tile, 4x4 per-thread micro-tile. a_mode 1: rows<400 from A, >=400 from Axt.
__device__ __forceinline__
void gemm_phase(const float* __restrict__ A, const float* __restrict__ Axt,
                const float* __restrict__ B, float* __restrict__ P,
                int lda, int ldb, int kc, int nvirt, int a_mode, int G,
                float (* __restrict__ Ast)[68], float (* __restrict__ Bs)[64]) {
    int t = threadIdx.x;
    int tx4 = (t & 15) * 4, ty4 = (t >> 4) * 4;
    int ar = t >> 2, ak = (t & 3) * 4;     // A staging: 64 rows x 16 k
    int bk = t >> 4, bn = (t & 15) * 4;    // B staging: 16 k x 64 cols

    for (int vb = blockIdx.x; vb < nvirt; vb += G) {
        int bx  = vb & (TILES_X - 1);
        int rem = vb >> 3;
        int by  = rem % TILES_Y;
        int bz  = rem / TILES_Y;
        int row0 = by * 64, col0 = bx * 64, kbase = bz * kc;
        float acc[4][4] = {};

        for (int kb = kbase; kb < kbase + kc; kb += 16) {
            {   // stage A (transposed)
                int gr = row0 + ar;
                float4 v = make_float4(0.f, 0.f, 0.f, 0.f);
                if (gr < N_NODES) {
                    const float* rowp;
                    if (a_mode == 1)
                        rowp = (gr < 400) ? (A + (size_t)gr * lda) : (Axt + (size_t)(gr - 400) * lda);
                    else
                        rowp = A + (size_t)gr * lda;
                    v = *(const float4*)(rowp + kb + ak);
                }
                Ast[ak + 0][ar] = v.x; Ast[ak + 1][ar] = v.y;
                Ast[ak + 2][ar] = v.z; Ast[ak + 3][ar] = v.w;
            }
            // stage B
            *(float4*)&Bs[bk][bn] = *(const float4*)&B[(size_t)(kb + bk) * ldb + col0 + bn];
            __syncthreads();
            #pragma unroll
            for (int kk = 0; kk < 16; kk++) {
                float4 a = *(const float4*)&Ast[kk][ty4];
                float4 b = *(const float4*)&Bs[kk][tx4];
                acc[0][0] += a.x*b.x; acc[0][1] += a.x*b.y; acc[0][2] += a.x*b.z; acc[0][3] += a.x*b.w;
                acc[1][0] += a.y*b.x; acc[1][1] += a.y*b.y; acc[1][2] += a.y*b.z; acc[1][3] += a.y*b.w;
                acc[2][0] += a.z*b.x; acc[2][1] += a.z*b.y; acc[2][2] += a.z*b.z; acc[2][3] += a.z*b.w;
                acc[3][0] += a.w*b.x; acc[3][1] += a.w*b.y; acc[3][2] += a.w*b.z; acc[3][3] += a.w*b.w;
            }
            __syncthreads();
        }

        float* Cout = P + (size_t)bz * (N_NODES * DIM);
        #pragma unroll
        for (int i = 0; i < 4; i++) {
            int gr = row0 + ty4 + i;
            if (gr < N_NODES)
                *(float4*)&Cout[(size_t)gr * DIM + col0 + tx4] =
                    make_float4(acc[i][0], acc[i][1], acc[i][2], acc[i][3]);
        }
    }
}

// ---------------- reduce split-K partials (ZG) + per-row attention logits ----------------
__device__ __forceinline__
void reduce_phase(const float* __restrict__ P,
                  const float* __restrict__ asrc, const float* __restrict__ adst,
                  float* __restrict__ h, float* __restrict__ als, float* __restrict__ ald,
                  int G, float* __restrict__ red) {
    const size_t S = (size_t)N_NODES * DIM;
    int t = threadIdx.x;
    for (int r = blockIdx.x; r < N_NODES; r += G) {
        size_t base = (size_t)r * DIM;
        float v0 = 0.f, v1 = 0.f;
        #pragma unroll
        for (int z = 0; z < ZG; z++) {
            v0 += P[z * S + base + t];
            v1 += P[z * S + base + t + 256];
        }
        h[base + t]       = v0;
        h[base + t + 256] = v1;
        float ps = v0 * asrc[t] + v1 * asrc[t + 256];
        float pd = v0 * adst[t] + v1 * adst[t + 256];
        #pragma unroll
        for (int o = 32; o > 0; o >>= 1) {
            ps += __shfl_down(ps, o);
            pd += __shfl_down(pd, o);
        }
        if ((t & 63) == 0) { red[t >> 6] = ps; red[4 + (t >> 6)] = pd; }
        __syncthreads();
        if (t == 0) als[r] = red[0] + red[1] + red[2] + red[3];
        if (t == 1) ald[r] = red[4] + red[5] + red[6] + red[7];
        __syncthreads();
    }
}

// ---------------- dense attention-matrix build from raw edge list ----------------
__device__ __forceinline__
void build_phase(const int* __restrict__ ei, const float* __restrict__ als,
                 const float* __restrict__ ald, float* __restrict__ W,
                 float* __restrict__ rs, int G, float* __restrict__ lrs) {
    int t = threadIdx.x;
    for (int l = t; l < N_NODES; l += 256) lrs[l] = 0.f;
    __syncthreads();
    const int stride = G * 256;
    for (int i = blockIdx.x * 256 + t; i < E_TOT; i += stride) {
        int s, d;
        if (i < E_RAW) { s = ei[i]; d = ei[E_RAW + i]; }
        else           { s = d = i - E_RAW; }
        float e = als[s] + ald[d];
        e = e > 0.f ? e : 0.2f * e;
        float ex = __expf(e);
        atomicAdd(&W[(size_t)d * WK + s], ex);
        atomicAdd(&lrs[d], ex);
    }
    __syncthreads();
    for (int l = t; l < N_NODES; l += 256)
        if (lrs[l] != 0.f) atomicAdd(&rs[l], lrs[l]);
    __syncthreads();   // lrs reused later
}

// ---------------- reduce agg partials (ZA), normalize, bias, activation ----------------
__device__ __forceinline__
void aggred_phase(const float* __restrict__ P, const float* __restrict__ rs,
                  const float* __restrict__ bias, float slope, float* __restrict__ o, int G) {
    const size_t S = (size_t)N_NODES * DIM;
    int t = threadIdx.x;
    for (int r = blockIdx.x; r < N_NODES; r += G) {
        size_t base = (size_t)r * DIM;
        float v0 = 0.f, v1 = 0.f;
        #pragma unroll
        for (int z = 0; z < ZA; z++) {
            v0 += P[z * S + base + t];
            v1 += P[z * S + base + t + 256];
        }
        float inv = 1.f / (rs[r] + 1e-16f);
        float a = v0 * inv + bias[t];
        float b = v1 * inv + bias[t + 256];
        o[base + t]       = a > 0.f ? a : slope * a;
        o[base + t + 256] = b > 0.f ? b : slope * b;
    }
}

// ---------------- final: reshape(512,650) @ fc_w + fc_b -> sigmoid ----------------
__device__ __forceinline__
void final_phase(const float* __restrict__ o2, const float* __restrict__ fcw,
                 const float* __restrict__ fcb, float* __restrict__ out,
                 int G, float* __restrict__ red) {
    int t = threadIdx.x;
    for (int b = blockIdx.x; b < 512; b += G) {
        float s = 0.f;
        for (int i = t; i < N_NODES; i += 256)
            s += o2[(size_t)b * N_NODES + i] * fcw[i];
        #pragma unroll
        for (int o = 32; o > 0; o >>= 1) s += __shfl_down(s, o);
        if ((t & 63) == 0) red[t >> 6] = s;
        __syncthreads();
        if (t == 0) {
            float v = red[0] + red[1] + red[2] + red[3] + fcb[0];
            out[b] = 1.f / (1.f + expf(-v));
        }
        __syncthreads();
    }
}

// ---------------- zero phase (W1d, W2d, rs1, rs2, h pad rows) ----------------
__device__ __forceinline__
void zero_phase(float* __restrict__ zbeg, int nz4, int G) {
    float4* z4 = (float4*)zbeg;
    int t = threadIdx.x;
    for (int i = blockIdx.x * 256 + t; i < nz4; i += G * 256)
        z4[i] = make_float4(0.f, 0.f, 0.f, 0.f);
}

// ---------------- the whole model, one cooperative kernel ----------------
__global__ __launch_bounds__(256, 2)
void gat_fused(const float* __restrict__ x_s, const float* __restrict__ x_t,
               const int* __restrict__ ei,
               const float* __restrict__ W1, const float* __restrict__ as1,
               const float* __restrict__ ad1, const float* __restrict__ b1,
               const float* __restrict__ W4, const float* __restrict__ as4,
               const float* __restrict__ ad4, const float* __restrict__ b4,
               const float* __restrict__ fcw, const float* __restrict__ fcb,
               float* __restrict__ out, float* __restrict__ ws) {
    __shared__ float Ast[16][68];
    __shared__ float Bs[16][64];
    __shared__ float lrs[N_NODES];
    __shared__ float red[8];

    const size_t S = (size_t)N_NODES * DIM;
    float* als1 = ws;
    float* ald1 = als1 + N_NODES;
    float* als2 = ald1 + N_NODES;
    float* ald2 = als2 + N_NODES;
    float* P    = ald2 + N_NODES;
    float* o1   = P + (size_t)ZG * S;
    float* o2   = o1 + S;
    float* h    = o2 + S;                        // WK x DIM (rows 650..671 zeroed)
    float* W1d  = h + (size_t)WK * DIM;
    float* W2d  = W1d + (size_t)N_NODES * WK;
    float* rs1  = W2d + (size_t)N_NODES * WK;
    float* rs2  = rs1 + N_NODES;

    cg::grid_group grid = cg::this_grid();
    const int G = gridDim.x;

    // ---- phase 1: zero region + feature GEMM layer 1 ----
    {
        const int nz4 = ((WK - N_NODES) * DIM + 2 * N_NODES * WK + 2 * N_NODES) / 4;
        zero_phase(h + (size_t)N_NODES * DIM, nz4, G);
    }
    gemm_phase(x_s, x_t, W1, P, DIM, DIM, 64, TILES_X * TILES_Y * ZG, 1, G, Ast, Bs);
    grid.sync();

    reduce_phase(P, as1, ad1, h, als1, ald1, G, red);
    grid.sync();

    build_phase(ei, als1, ald1, W1d, rs1, G, lrs);
    grid.sync();

    gemm_phase(W1d, nullptr, h, P, WK, DIM, 112, TILES_X * TILES_Y * ZA, 0, G, Ast, Bs);
    grid.sync();

    aggred_phase(P, rs1, b1, 0.0f, o1, G);
    grid.sync();

    // ---- layer 2 ----
    gemm_phase(o1, nullptr, W4, P, DIM, DIM, 64, TILES_X * TILES_Y * ZG, 0, G, Ast, Bs);
    grid.sync();

    reduce_phase(P, as4, ad4, h, als2, ald2, G, red);
    grid.sync();

    build_phase(ei, als2, ald2, W2d, rs2, G, lrs);
    grid.sync();

    gemm_phase(W2d, nullptr, h, P, WK, DIM, 112, TILES_X * TILES_Y * ZA, 0, G, Ast, Bs);
    grid.sync();

    aggred_phase(P, rs2, b4, 0.01f, o2, G);
    grid.sync();

    final_phase(o2, fcw, fcb, out, G, red);
}

// ---------------- standalone fallback kernels (proven R1 pipeline) ----------------
__global__ __launch_bounds__(256)
void k_gemm(const float* __restrict__ A, const float* __restrict__ Axt,
            const float* __restrict__ B, float* __restrict__ P,
            int lda, int ldb, int kc, int nvirt, int a_mode) {
    __shared__ float Ast[16][68];
    __shared__ float Bs[16][64];
    gemm_phase(A, Axt, B, P, lda, ldb, kc, nvirt, a_mode, gridDim.x, Ast, Bs);
}

__global__ __launch_bounds__(256)
void k_reduce(const float* __restrict__ P, const float* __restrict__ asrc,
              const float* __restrict__ adst, float* __restrict__ h,
              float* __restrict__ als, float* __restrict__ ald) {
    __shared__ float red[8];
    reduce_phase(P, asrc, adst, h, als, ald, gridDim.x, red);
}

__global__ __launch_bounds__(256)
void k_build(const int* __restrict__ ei, const float* __restrict__ als,
             const float* __restrict__ ald, float* __restrict__ W,
             float* __restrict__ rs) {
    __shared__ float lrs[N_NODES];
    build_phase(ei, als, ald, W, rs, gridDim.x, lrs);
}

__global__ __launch_bounds__(256)
void k_aggred(const float* __restrict__ P, const float* __restrict__ rs,
              const float* __restrict__ bias, float slope, float* __restrict__ o) {
    aggred_phase(P, rs, bias, slope, o, gridDim.x);
}

__global__ __launch_bounds__(256)
void k_final(const float* __restrict__ o2, const float* __restrict__ fcw,
             const float* __restrict__ fcb, float* __restrict__ out) {
    __shared__ float red[8];
    final_phase(o2, fcw, fcb, out, gridDim.x, red);
}

extern "C" void kernel_launch(void* const* d_in, const int* in_sizes, int n_in,
                              void* d_out, int out_size, void* d_ws, size_t ws_size,
                              hipStream_t stream) {
    const float* x_s   = (const float*)d_in[0];
    const float* x_t   = (const float*)d_in[1];
    const int*   ei    = (const int*)d_in[2];
    const float* W1    = (const float*)d_in[5];
    const float* asrc1 = (const float*)d_in[6];
    const float* adst1 = (const float*)d_in[7];
    const float* b1    = (const float*)d_in[8];
    const float* W4    = (const float*)d_in[9];
    const float* asrc4 = (const float*)d_in[10];
    const float* adst4 = (const float*)d_in[11];
    const float* b4    = (const float*)d_in[12];
    const float* fcw   = (const float*)d_in[13];
    const float* fcb   = (const float*)d_in[14];
    float* out = (float*)d_out;
    float* ws  = (float*)d_ws;

    const size_t S = (size_t)N_NODES * DIM;
    float* als1 = ws;
    float* ald1 = als1 + N_NODES;
    float* als2 = ald1 + N_NODES;
    float* ald2 = als2 + N_NODES;
    float* P    = ald2 + N_NODES;
    float* o1   = P + (size_t)ZG * S;
    float* o2   = o1 + S;
    float* h    = o2 + S;
    float* W1d  = h + (size_t)WK * DIM;
    float* W2d  = W1d + (size_t)N_NODES * WK;
    float* rs1  = W2d + (size_t)N_NODES * WK;
    float* rs2  = rs1 + N_NODES;

    // runtime-sized cooperative grid (cached)
    static int coop_blocks = -2;   // -2 = not yet probed, -1 = unusable
    if (coop_blocks == -2) {
        int maxB = 0;
        hipError_t e = hipOccupancyMaxActiveBlocksPerMultiprocessor(
            &maxB, (const void*)gat_fused, 256, 0);
        if (e == hipSuccess && maxB >= 1) {
            hipDeviceProp_t prop;
            int dev = 0;
            hipGetDevice(&dev);
            if (hipGetDeviceProperties(&prop, dev) == hipSuccess && prop.multiProcessorCount > 0) {
                long cap = (long)maxB * prop.multiProcessorCount;
                coop_blocks = (int)(cap < 512 ? cap : 512);
            } else {
                coop_blocks = -1;
            }
        } else {
            coop_blocks = -1;
        }
    }

    bool done = false;
    if (coop_blocks > 0) {
        void* args[] = {
            (void*)&x_s, (void*)&x_t, (void*)&ei,
            (void*)&W1, (void*)&asrc1, (void*)&adst1, (void*)&b1,
            (void*)&W4, (void*)&asrc4, (void*)&adst4, (void*)&b4,
            (void*)&fcw, (void*)&fcb, (void*)&out, (void*)&ws
        };
        hipError_t e = hipLaunchCooperativeKernel((const void*)gat_fused,
                                                  dim3(coop_blocks), dim3(256),
                                                  args, 0, stream);
        if (e == hipSuccess) done = true;
        else coop_blocks = -1;     // never retry the coop path
    }

    if (!done) {
        // -------- fallback: proven multi-kernel pipeline --------
        float* zbeg = h + (size_t)N_NODES * DIM;
        size_t zbytes = (size_t)((WK - N_NODES) * DIM
                               + 2 * N_NODES * WK
                               + 2 * N_NODES) * sizeof(float);
        hipMemsetAsync(zbeg, 0, zbytes, stream);

        k_gemm<<<512, 256, 0, stream>>>(x_s, x_t, W1, P, DIM, DIM, 64, TILES_X * TILES_Y * ZG, 1);
        k_reduce<<<N_NODES, 256, 0, stream>>>(P, asrc1, adst1, h, als1, ald1);
        k_build<<<128, 256, 0, stream>>>(ei, als1, ald1, W1d, rs1);
        k_gemm<<<512, 256, 0, stream>>>(W1d, nullptr, h, P, WK, DIM, 112, TILES_X * TILES_Y * ZA, 0);
        k_aggred<<<N_NODES, 256, 0, stream>>>(P, rs1, b1, 0.0f, o1);

        k_gemm<<<512, 256, 0, stream>>>(o1, nullptr, W4, P, DIM, DIM, 64, TILES_X * TILES_Y * ZG, 0);
        k_reduce<<<N_NODES, 256, 0, stream>>>(P, asrc4, adst4, h, als2, ald2);
        k_build<<<128, 256, 0, stream>>>(ei, als2, ald2, W2d, rs2);
        k_gemm<<<512, 256, 0, stream>>>(W2d, nullptr, h, P, WK, DIM, 112, TILES_X * TILES_Y * ZA, 0);
        k_aggred<<<N_NODES, 256, 0, stream>>>(P, rs2, b4, 0.01f, o2);

        k_final<<<512, 256, 0, stream>>>(o2, fcw, fcb, out);
    }
}

// Round 5
// 255.605 us; speedup vs baseline: 2.0541x; 2.0541x over previous
//
#include <hip/hip_runtime.h>
#include <math.h>

#define N_NODES 650
#define DIM     512
#define E_RAW   150000
#define E_TOT   150650
#define WK      672              // padded row length for dense attention matrix (672 = 42*16)

// =============== feature GEMM + logits ===============
// h[r,c] = (A @ B)[r,c]   (M=650, K=512, N=512), 64x64 tile, 4x4 micro-tile.
// Epilogue: h store + atomicAdd per-row logit partials als[r] += h_tile[r,:]·asrc[:],
// ald likewise. a_mode 1: rows<400 from A (x_s), >=400 from Axt (x_t).
__global__ __launch_bounds__(256)
void k_feat(const float* __restrict__ A, const float* __restrict__ Axt,
            const float* __restrict__ B,
            const float* __restrict__ asrc, const float* __restrict__ adst,
            float* __restrict__ h, float* __restrict__ als, float* __restrict__ ald,
            int a_mode) {
    __shared__ float Ast[16][68];   // transposed A tile (stride 68: 16B-aligned, 2-way banks)
    __shared__ float Bs[16][64];
    int t = threadIdx.x;
    int tx4 = (t & 15) * 4, ty4 = (t >> 4) * 4;
    int row0 = blockIdx.y * 64, col0 = blockIdx.x * 64;
    int ar = t >> 2, ak = (t & 3) * 4;     // A staging: 64 rows x 16 k
    int bk = t >> 4, bn = (t & 15) * 4;    // B staging: 16 k x 64 cols
    float acc[4][4] = {};

    for (int kb = 0; kb < DIM; kb += 16) {
        {
            int gr = row0 + ar;
            float4 v = make_float4(0.f, 0.f, 0.f, 0.f);
            if (gr < N_NODES) {
                const float* rowp = (a_mode == 1)
                    ? ((gr < 400) ? A + (size_t)gr * DIM : Axt + (size_t)(gr - 400) * DIM)
                    : A + (size_t)gr * DIM;
                v = *(const float4*)(rowp + kb + ak);
            }
            Ast[ak + 0][ar] = v.x; Ast[ak + 1][ar] = v.y;
            Ast[ak + 2][ar] = v.z; Ast[ak + 3][ar] = v.w;
        }
        *(float4*)&Bs[bk][bn] = *(const float4*)&B[(size_t)(kb + bk) * DIM + col0 + bn];
        __syncthreads();
        #pragma unroll
        for (int kk = 0; kk < 16; kk++) {
            float4 a = *(const float4*)&Ast[kk][ty4];
            float4 b = *(const float4*)&Bs[kk][tx4];
            acc[0][0] += a.x*b.x; acc[0][1] += a.x*b.y; acc[0][2] += a.x*b.z; acc[0][3] += a.x*b.w;
            acc[1][0] += a.y*b.x; acc[1][1] += a.y*b.y; acc[1][2] += a.y*b.z; acc[1][3] += a.y*b.w;
            acc[2][0] += a.z*b.x; acc[2][1] += a.z*b.y; acc[2][2] += a.z*b.z; acc[2][3] += a.z*b.w;
            acc[3][0] += a.w*b.x; acc[3][1] += a.w*b.y; acc[3][2] += a.w*b.z; acc[3][3] += a.w*b.w;
        }
        __syncthreads();
    }

    // epilogue: store h + logit partials
    float4 as4 = *(const float4*)&asrc[col0 + tx4];
    float4 ad4 = *(const float4*)&adst[col0 + tx4];
    #pragma unroll
    for (int i = 0; i < 4; i++) {
        int gr = row0 + ty4 + i;
        float sa = acc[i][0]*as4.x + acc[i][1]*as4.y + acc[i][2]*as4.z + acc[i][3]*as4.w;
        float sd = acc[i][0]*ad4.x + acc[i][1]*ad4.y + acc[i][2]*ad4.z + acc[i][3]*ad4.w;
        #pragma unroll
        for (int o = 8; o > 0; o >>= 1) {     // reduce across the 16 col-threads
            sa += __shfl_down(sa, o, 16);
            sd += __shfl_down(sd, o, 16);
        }
        if (gr < N_NODES) {
            *(float4*)&h[(size_t)gr * DIM + col0 + tx4] =
                make_float4(acc[i][0], acc[i][1], acc[i][2], acc[i][3]);
            if ((t & 15) == 0) {
                atomicAdd(&als[gr], sa);
                atomicAdd(&ald[gr], sd);
            }
        }
    }
}

// =============== dense attention-matrix build from raw edge list ===============
// W[d][s] += exp(leaky(als[s]+ald[d])), rs[d] += same (rowsum). W, rs pre-zeroed.
__global__ __launch_bounds__(256)
void k_build(const int* __restrict__ ei, const float* __restrict__ als,
             const float* __restrict__ ald, float* __restrict__ W,
             float* __restrict__ rs) {
    __shared__ float lrs[N_NODES];
    int t = threadIdx.x;
    for (int l = t; l < N_NODES; l += 256) lrs[l] = 0.f;
    __syncthreads();
    const int stride = gridDim.x * 256;
    for (int i = blockIdx.x * 256 + t; i < E_TOT; i += stride) {
        int s, d;
        if (i < E_RAW) { s = ei[i]; d = ei[E_RAW + i]; }
        else           { s = d = i - E_RAW; }
        float e = als[s] + ald[d];
        e = e > 0.f ? e : 0.2f * e;
        float ex = __expf(e);
        atomicAdd(&W[(size_t)d * WK + s], ex);
        atomicAdd(&lrs[d], ex);
    }
    __syncthreads();
    for (int l = t; l < N_NODES; l += 256)
        if (lrs[l] != 0.f) atomicAdd(&rs[l], lrs[l]);
}

// =============== agg GEMM + normalize/bias/activation ===============
// o[d,c] = act( (W @ h)[d,c] / rs[d] + bias[c] )   (M=650, K=672, N=512)
__global__ __launch_bounds__(256)
void k_agg(const float* __restrict__ W, const float* __restrict__ Bm,
           const float* __restrict__ rs, const float* __restrict__ bias,
           float slope, float* __restrict__ o) {
    __shared__ float Ast[16][68];
    __shared__ float Bs[16][64];
    int t = threadIdx.x;
    int tx4 = (t & 15) * 4, ty4 = (t >> 4) * 4;
    int row0 = blockIdx.y * 64, col0 = blockIdx.x * 64;
    int ar = t >> 2, ak = (t & 3) * 4;
    int bk = t >> 4, bn = (t & 15) * 4;
    float acc[4][4] = {};

    for (int kb = 0; kb < WK; kb += 16) {
        {
            int gr = row0 + ar;
            float4 v = make_float4(0.f, 0.f, 0.f, 0.f);
            if (gr < N_NODES)
                v = *(const float4*)(W + (size_t)gr * WK + kb + ak);
            Ast[ak + 0][ar] = v.x; Ast[ak + 1][ar] = v.y;
            Ast[ak + 2][ar] = v.z; Ast[ak + 3][ar] = v.w;
        }
        *(float4*)&Bs[bk][bn] = *(const float4*)&Bm[(size_t)(kb + bk) * DIM + col0 + bn];
        __syncthreads();
        #pragma unroll
        for (int kk = 0; kk < 16; kk++) {
            float4 a = *(const float4*)&Ast[kk][ty4];
            float4 b = *(const float4*)&Bs[kk][tx4];
            acc[0][0] += a.x*b.x; acc[0][1] += a.x*b.y; acc[0][2] += a.x*b.z; acc[0][3] += a.x*b.w;
            acc[1][0] += a.y*b.x; acc[1][1] += a.y*b.y; acc[1][2] += a.y*b.z; acc[1][3] += a.y*b.w;
            acc[2][0] += a.z*b.x; acc[2][1] += a.z*b.y; acc[2][2] += a.z*b.z; acc[2][3] += a.z*b.w;
            acc[3][0] += a.w*b.x; acc[3][1] += a.w*b.y; acc[3][2] += a.w*b.z; acc[3][3] += a.w*b.w;
        }
        __syncthreads();
    }

    float4 bb = *(const float4*)&bias[col0 + tx4];
    #pragma unroll
    for (int i = 0; i < 4; i++) {
        int gr = row0 + ty4 + i;
        if (gr < N_NODES) {
            float inv = 1.f / (rs[gr] + 1e-16f);
            float v0 = acc[i][0] * inv + bb.x;
            float v1 = acc[i][1] * inv + bb.y;
            float v2 = acc[i][2] * inv + bb.z;
            float v3 = acc[i][3] * inv + bb.w;
            v0 = v0 > 0.f ? v0 : slope * v0;
            v1 = v1 > 0.f ? v1 : slope * v1;
            v2 = v2 > 0.f ? v2 : slope * v2;
            v3 = v3 > 0.f ? v3 : slope * v3;
            *(float4*)&o[(size_t)gr * DIM + col0 + tx4] = make_float4(v0, v1, v2, v3);
        }
    }
}

// =============== final: reshape(512,650) @ fc_w + fc_b -> sigmoid ===============
__global__ void k_final(const float* __restrict__ o2,
                        const float* __restrict__ fcw,
                        const float* __restrict__ fcb,
                        float* __restrict__ out) {
    int b = blockIdx.x * 4 + (threadIdx.x >> 6);
    int lane = threadIdx.x & 63;
    if (b >= 512) return;
    float s = 0.f;
    for (int i = lane; i < N_NODES; i += 64)
        s += o2[(size_t)b * N_NODES + i] * fcw[i];
    #pragma unroll
    for (int o = 32; o > 0; o >>= 1) s += __shfl_down(s, o);
    if (lane == 0) out[b] = 1.f / (1.f + expf(-(s + fcb[0])));
}

extern "C" void kernel_launch(void* const* d_in, const int* in_sizes, int n_in,
                              void* d_out, int out_size, void* d_ws, size_t ws_size,
                              hipStream_t stream) {
    const float* x_s   = (const float*)d_in[0];
    const float* x_t   = (const float*)d_in[1];
    const int*   ei    = (const int*)d_in[2];
    const float* W1    = (const float*)d_in[5];
    const float* asrc1 = (const float*)d_in[6];
    const float* adst1 = (const float*)d_in[7];
    const float* b1    = (const float*)d_in[8];
    const float* W4    = (const float*)d_in[9];
    const float* asrc4 = (const float*)d_in[10];
    const float* adst4 = (const float*)d_in[11];
    const float* b4    = (const float*)d_in[12];
    const float* fcw   = (const float*)d_in[13];
    const float* fcb   = (const float*)d_in[14];
    float* out = (float*)d_out;

    // workspace layout: [ h (672x512) | als1 ald1 als2 ald2 rs1 rs2 | W1d | W2d | o1 | o2 ]
    // zero span = h pad rows (650..671) .. end of W2d (contiguous)
    float* ws   = (float*)d_ws;
    float* h    = ws;                                // WK*DIM = 344064
    float* als1 = h + (size_t)WK * DIM;              // 650
    float* ald1 = als1 + N_NODES;
    float* als2 = ald1 + N_NODES;
    float* ald2 = als2 + N_NODES;
    float* rs1  = ald2 + N_NODES;
    float* rs2  = rs1 + N_NODES;
    float* W1d  = rs2 + N_NODES;                     // 650*672
    float* W2d  = W1d + (size_t)N_NODES * WK;        // 650*672
    float* o1   = W2d + (size_t)N_NODES * WK;        // 332800
    float* o2   = o1 + (size_t)N_NODES * DIM;        // 332800

    float* zbeg = h + (size_t)N_NODES * DIM;         // start of h pad rows
    size_t zbytes = (size_t)((WK - N_NODES) * DIM    // h pad rows: 22*512
                           + 6 * N_NODES             // als1,ald1,als2,ald2,rs1,rs2
                           + 2 * N_NODES * WK)       // W1d, W2d
                    * sizeof(float);
    hipMemsetAsync(zbeg, 0, zbytes, stream);

    dim3 gT(DIM / 64, (N_NODES + 63) / 64);          // 8 x 11 = 88 blocks

    // ---- layer 1 ----
    k_feat<<<gT, 256, 0, stream>>>(x_s, x_t, W1, asrc1, adst1, h, als1, ald1, 1);
    k_build<<<128, 256, 0, stream>>>(ei, als1, ald1, W1d, rs1);
    k_agg<<<gT, 256, 0, stream>>>(W1d, h, rs1, b1, 0.0f, o1);

    // ---- layer 2 ----
    k_feat<<<gT, 256, 0, stream>>>(o1, nullptr, W4, asrc4, adst4, h, als2, ald2, 0);
    k_build<<<128, 256, 0, stream>>>(ei, als2, ald2, W2d, rs2);
    k_agg<<<gT, 256, 0, stream>>>(W2d, h, rs2, b4, 0.01f, o2);

    // ---- final ----
    k_final<<<128, 256, 0, stream>>>(o2, fcw, fcb, out);
}